// Round 16
// baseline (517.572 us; speedup 1.0000x reference)
//
#include <hip/hip_runtime.h>
#include <hip/hip_bf16.h>
#include <math.h>

#define N_NODES  8192
#define N_EDGES  49152
#define E_TOT    57344   // edges + self-loops
#define IN_F     128
#define HID      64
#define NH1      64
#define NH2      5
#define OUT_F    32
#define F1       4096    // NH1*HID
#define F2       160     // NH2*OUT_F
#define N_BONDS  64
#define ET1      16      // l1f edge-tile
#define KS2      2       // gemm2 k-split (partial buffers)

typedef short bf16x8 __attribute__((ext_vector_type(8)));
typedef float f32x4  __attribute__((ext_vector_type(4)));

__device__ __forceinline__ float lrelu(float x){ return x > 0.f ? x : 0.2f*x; }

__device__ __forceinline__ unsigned short bf16_rne(float f){
    unsigned u = __float_as_uint(f);
    unsigned r = u + 0x7FFF + ((u >> 16) & 1);
    return (unsigned short)(r >> 16);
}
__device__ __forceinline__ float bf16f(unsigned short h){
    return __uint_as_float((unsigned)h << 16);
}

// ---------------- CSR build (sort edges by dst) ----------------
__global__ void k_init_counts(int* counts){
    int i = blockIdx.x*256 + threadIdx.x;
    if (i < N_NODES) counts[i] = 1;   // self-loop
}
__global__ void k_count(const int* __restrict__ ei, int* counts){
    int i = blockIdx.x*256 + threadIdx.x;
    if (i < N_EDGES) atomicAdd(&counts[ei[N_EDGES + i]], 1);
}
__global__ __launch_bounds__(1024) void k_scan(const int* __restrict__ counts,
                                               int* __restrict__ row_start,
                                               int* __restrict__ cursor){
    __shared__ int sd[1024];
    int t = threadIdx.x;
    int v[8]; int sum = 0;
    #pragma unroll
    for (int i=0;i<8;i++){ v[i] = counts[t*8+i]; sum += v[i]; }
    sd[t] = sum; __syncthreads();
    for (int off=1; off<1024; off<<=1){
        int vv = (t >= off) ? sd[t-off] : 0;
        __syncthreads();
        sd[t] += vv;
        __syncthreads();
    }
    int run = sd[t] - sum;  // exclusive prefix
    #pragma unroll
    for (int i=0;i<8;i++){ row_start[t*8+i] = run; cursor[t*8+i] = run; run += v[i]; }
    if (t == 1023) row_start[N_NODES] = run;
}
__global__ void k_fill(const int* __restrict__ ei, int* cursor, int* __restrict__ csr_src){
    int i = blockIdx.x*256 + threadIdx.x;
    if (i >= E_TOT) return;
    int s, d;
    if (i < N_EDGES){ s = ei[i]; d = ei[N_EDGES + i]; }
    else { s = i - N_EDGES; d = s; }
    int pos = atomicAdd(&cursor[d], 1);
    csr_src[pos] = s;
}

// ---- pack W1 fp32 -> split-bf16 B-fragment order: [hg][ks][ct][lane][8] ----
__global__ void k_packw1d(const float* __restrict__ W1,
                          unsigned short* __restrict__ fh, unsigned short* __restrict__ fl){
    int g = blockIdx.x*256 + threadIdx.x;            // 64*4*4*64 = 65536 groups
    int lane = g & 63, ct = (g >> 6) & 3, ks = (g >> 8) & 3, hg = g >> 10;
    int col = hg*64 + ct*16 + (lane & 15);
    int k = ks*32 + (lane >> 4)*8;
    const float* src = W1 + (size_t)col*IN_F + k;
    bf16x8 hv, lv;
    #pragma unroll
    for (int j=0;j<8;j++){
        float f = src[j];
        unsigned short hb = bf16_rne(f);
        hv[j] = (short)hb;
        lv[j] = (short)bf16_rne(f - bf16f(hb));
    }
    *(bf16x8*)(fh + (size_t)g*8) = hv;
    *(bf16x8*)(fl + (size_t)g*8) = lv;
}

// ---- pack W2 fp32 -> split-bf16 B-fragment order: [kc][ni][lane][8] ----
__global__ void k_packw2d(const float* __restrict__ W2,
                          unsigned short* __restrict__ fh, unsigned short* __restrict__ fl){
    int g = blockIdx.x*256 + threadIdx.x;            // 128*10*64 = 81920 groups
    int lane = g & 63, ni = (g >> 6) % 10, kc = g / 640;
    int n = ni*16 + (lane & 15);
    int k = kc*32 + (lane >> 4)*8;
    const float* src = W2 + (size_t)n*F1 + k;
    bf16x8 hv, lv;
    #pragma unroll
    for (int j=0;j<8;j++){
        float f = src[j];
        unsigned short hb = bf16_rne(f);
        hv[j] = (short)hb;
        lv[j] = (short)bf16_rne(f - bf16f(hb));
    }
    *(bf16x8*)(fh + (size_t)g*8) = hv;
    *(bf16x8*)(fl + (size_t)g*8) = lv;
}

// ------- attention vectors: vsT[k][h] = sum_c a_s[h,c] * W1[h*64+c, k] -------
__global__ __launch_bounds__(128) void k_attvec(const float* __restrict__ W1,
        const float* __restrict__ a_s, const float* __restrict__ a_d,
        float* __restrict__ vsT, float* __restrict__ vdT){
    int h = blockIdx.x, k = threadIdx.x;
    float s = 0.f, d = 0.f;
    for (int c = 0; c < HID; c++){
        float w = W1[(size_t)(h*HID + c)*IN_F + k];
        s += a_s[h*HID + c] * w;
        d += a_d[h*HID + c] * w;
    }
    vsT[k*NH1 + h] = s;
    vdT[k*NH1 + h] = d;
}

// ---------- alpha dots from x: as1[n,h] = x[n,:] . vsT[:,h] ------------------
__global__ __launch_bounds__(128) void k_alpha1x(const float* __restrict__ x,
        const float* __restrict__ vsT, const float* __restrict__ vdT,
        float* __restrict__ as1, float* __restrict__ ad1){
    int n = blockIdx.x, t = threadIdx.x;
    __shared__ float xs[IN_F];
    xs[t] = x[(size_t)n*IN_F + t];
    __syncthreads();
    if (t < NH1){
        float s = 0.f, d = 0.f;
        for (int k = 0; k < IN_F; k++){
            float xv = xs[k];
            s += xv * vsT[k*NH1 + t];
            d += xv * vdT[k*NH1 + t];
        }
        as1[n*NH1 + t] = s;
        ad1[n*NH1 + t] = d;
    }
}

// ------- FUSED layer 1: x-space agg (block-coop) + MFMA + bias/ELU -> x1 frag
// grid (N/16, NH1/4); block 256 = 4 waves. Block owns 16 nodes; wave owns one
// head (h0+wave). Edge-tiles staged in LDS (R13's proven pattern, 16 nodes at
// once); thread (node,fs) accumulates 4 heads x 8 feats in registers; denom
// free. Then per-wave: reg->LDS A-tile (136-pad: 2-way banks), A-frags to
// regs, LDS reused for C-tile, split-bf16 MFMA vs frag-packed W1, bias/ELU,
// frag-packed x1 write (1KB-contiguous per (mtile,ksg) -- no write scatter).
__global__ __launch_bounds__(256) void k_l1f(const float* __restrict__ x,
        const float* __restrict__ as1, const float* __restrict__ ad1,
        const int* __restrict__ row_start, const int* __restrict__ csr_src,
        const unsigned short* __restrict__ w1fh, const unsigned short* __restrict__ w1fl,
        const float* __restrict__ b1,
        unsigned short* __restrict__ x1fh, unsigned short* __restrict__ x1fl){
    __shared__ float xs[ET1][IN_F];          // 8 KB
    __shared__ float wt[ET1][4];
    __shared__ int   rs[17];
    __shared__ unsigned short th[4][16][136]; // per-wave A-tile hi (17.4 KB)
    __shared__ unsigned short tl[4][16][136]; // per-wave A-tile lo (17.4 KB)
    int t = threadIdx.x;
    int wave = t >> 6, lane = t & 63;
    int q = lane >> 4, l16 = lane & 15;
    int node = t >> 4, fs = t & 15;          // consume mapping
    int n0 = blockIdx.x * 16;
    int h0 = blockIdx.y * 4;
    int mtile = blockIdx.x;
    if (t < 17) rs[t] = row_start[n0 + t];
    __syncthreads();
    int eb0 = rs[0], eb1 = rs[16];
    int my0 = rs[node], my1 = rs[node+1];
    float4 a4 = *(const float4*)(ad1 + (size_t)(n0+node)*NH1 + h0);
    float adv[4] = {a4.x, a4.y, a4.z, a4.w};
    float acc[4][8] = {};
    float D[4] = {0.f, 0.f, 0.f, 0.f};
    for (int tb = eb0; tb < eb1; tb += ET1){
        int ne = min(ET1, eb1 - tb);
        for (int idx = t; idx < ne*32; idx += 256){
            int e = idx >> 5, f4 = idx & 31;
            int src = csr_src[tb + e];
            *(float4*)&xs[e][f4*4] = *(const float4*)(x + (size_t)src*IN_F + f4*4);
        }
        for (int idx = t; idx < ne*4; idx += 256){
            int e = idx >> 2, h = idx & 3;
            int ge = tb + e;
            int src = csr_src[ge];
            int dl = 0;
            while (rs[dl+1] <= ge) dl++;
            wt[e][h] = expf(lrelu(as1[(size_t)src*NH1 + h0 + h]
                                  + ad1[(size_t)(n0+dl)*NH1 + h0 + h]));
        }
        __syncthreads();
        int lo = my0 > tb ? my0 : tb;
        int hi = my1 < tb + ne ? my1 : tb + ne;
        for (int ge = lo; ge < hi; ge++){
            int e = ge - tb;
            float4 v0 = *(const float4*)&xs[e][fs*8];
            float4 v1 = *(const float4*)&xs[e][fs*8 + 4];
            float xv[8] = {v0.x,v0.y,v0.z,v0.w,v1.x,v1.y,v1.z,v1.w};
            #pragma unroll
            for (int h=0;h<4;h++){
                float w = wt[e][h];
                D[h] += w;
                #pragma unroll
                for (int j=0;j<8;j++) acc[h][j] += w*xv[j];
            }
        }
        __syncthreads();
    }
    // reg -> per-head A-tiles (thread (node,fs) writes 8 contiguous shorts/head)
    #pragma unroll
    for (int h=0;h<4;h++){
        float dinv = 1.f / D[h];
        #pragma unroll
        for (int j=0;j<8;j++){
            float f = acc[h][j] * dinv;
            unsigned short hb = bf16_rne(f);
            th[h][node][fs*8 + j] = hb;
            tl[h][node][fs*8 + j] = bf16_rne(f - bf16f(hb));
        }
    }
    __syncthreads();
    // wave handles head hg = h0 + wave; load A-frags to regs, then LDS reused
    int hg = h0 + wave;
    bf16x8 ah[4], al[4];
    #pragma unroll
    for (int ks=0;ks<4;ks++){
        ah[ks] = *(const bf16x8*)&th[wave][l16][ks*32 + q*8];
        al[ks] = *(const bf16x8*)&tl[wave][l16][ks*32 + q*8];
    }
    f32x4 cacc[4] = {};
    #pragma unroll
    for (int ks=0;ks<4;ks++)
        #pragma unroll
        for (int ct=0;ct<4;ct++){
            size_t r = (((size_t)hg*4 + ks)*4 + ct)*512 + lane*8;
            bf16x8 bh = *(const bf16x8*)(w1fh + r);
            bf16x8 bl = *(const bf16x8*)(w1fl + r);
            cacc[ct] = __builtin_amdgcn_mfma_f32_16x16x32_bf16(ah[ks], bh, cacc[ct], 0,0,0);
            cacc[ct] = __builtin_amdgcn_mfma_f32_16x16x32_bf16(ah[ks], bl, cacc[ct], 0,0,0);
            cacc[ct] = __builtin_amdgcn_mfma_f32_16x16x32_bf16(al[ks], bh, cacc[ct], 0,0,0);
        }
    // bias + ELU + split into this wave's (now dead) A-tile region as C-tile
    #pragma unroll
    for (int ct=0;ct<4;ct++){
        float b = b1[hg*64 + ct*16 + l16];
        #pragma unroll
        for (int i=0;i<4;i++){
            float v = cacc[ct][i] + b;
            float o = v > 0.f ? v : expm1f(v);
            unsigned short hb = bf16_rne(o);
            th[wave][q*4 + i][ct*16 + l16] = hb;
            tl[wave][q*4 + i][ct*16 + l16] = bf16_rne(o - bf16f(hb));
        }
    }
    // per-wave LDS ops: in-order, no cross-wave sharing -> no barrier needed
    #pragma unroll
    for (int ksgl=0; ksgl<2; ksgl++){
        bf16x8 fh = *(const bf16x8*)&th[wave][l16][ksgl*32 + q*8];
        bf16x8 fl = *(const bf16x8*)&tl[wave][l16][ksgl*32 + q*8];
        size_t o = ((size_t)mtile*128 + hg*2 + ksgl)*512 + lane*8;
        *(bf16x8*)(x1fh + o) = fh;
        *(bf16x8*)(x1fl + o) = fl;
    }
}

// ------- GEMM2 (MFMA split-bf16, all-fragment-packed, single dispatch) -------
// grid (256, KS2); block 256 = 4 waves (2 m-tiles x 2 n-halves of 80).
// All loads lane-contiguous 1KB streams; direct store to own partial.
__global__ __launch_bounds__(256) void k_gemm2c(
        const unsigned short* __restrict__ x1fh, const unsigned short* __restrict__ x1fl,
        const unsigned short* __restrict__ w2fh, const unsigned short* __restrict__ w2fl,
        float* __restrict__ P){
    int wave = threadIdx.x >> 6, lane = threadIdx.x & 63;
    int wm = wave & 1, wn = wave >> 1;
    int q = lane >> 4, l16 = lane & 15;
    int mtile = blockIdx.x*2 + wm;
    int ks2 = blockIdx.y;
    int ks0 = ks2 * 64;
    const unsigned short* Ah = x1fh + ((size_t)mtile*128 + ks0)*512 + lane*8;
    const unsigned short* Al = x1fl + ((size_t)mtile*128 + ks0)*512 + lane*8;
    const unsigned short* Bh = w2fh + ((size_t)ks0*10 + wn*5)*512 + lane*8;
    const unsigned short* Bl = w2fl + ((size_t)ks0*10 + wn*5)*512 + lane*8;
    f32x4 acc[5] = {};
    #pragma unroll 4
    for (int t = 0; t < 64; t++){
        bf16x8 ah = *(const bf16x8*)(Ah + (size_t)t*512);
        bf16x8 al = *(const bf16x8*)(Al + (size_t)t*512);
        bf16x8 bh[5], bl[5];
        #pragma unroll
        for (int ni=0;ni<5;ni++){
            bh[ni] = *(const bf16x8*)(Bh + (size_t)(t*10 + ni)*512);
            bl[ni] = *(const bf16x8*)(Bl + (size_t)(t*10 + ni)*512);
        }
        #pragma unroll
        for (int ni=0;ni<5;ni++){
            acc[ni] = __builtin_amdgcn_mfma_f32_16x16x32_bf16(ah, bh[ni], acc[ni], 0,0,0);
            acc[ni] = __builtin_amdgcn_mfma_f32_16x16x32_bf16(ah, bl[ni], acc[ni], 0,0,0);
            acc[ni] = __builtin_amdgcn_mfma_f32_16x16x32_bf16(al, bh[ni], acc[ni], 0,0,0);
        }
    }
    float* outp = P + (size_t)ks2 * N_NODES * F2;
    #pragma unroll
    for (int ni=0;ni<5;ni++)
        #pragma unroll
        for (int i=0;i<4;i++)
            outp[(size_t)(mtile*16 + q*4 + i)*F2 + wn*80 + ni*16 + l16] = acc[ni][i];
}

// ---------------- reduce KS2 partials -> h2 ----------------
__global__ __launch_bounds__(256) void k_reduce(const float* __restrict__ P,
                                                float* __restrict__ h2){
    const int NV = N_NODES*F2/4;
    int i = blockIdx.x*256 + threadIdx.x;
    float4 a = ((const float4*)P)[i];
    #pragma unroll
    for (int kb = 1; kb < KS2; kb++){
        float4 b = ((const float4*)P)[(size_t)kb*NV + i];
        a.x += b.x; a.y += b.y; a.z += b.z; a.w += b.w;
    }
    ((float4*)h2)[i] = a;
}

// ---------------- attention dots, layer 2 ----------------
__global__ __launch_bounds__(64) void k_alpha2(const float* __restrict__ h2,
        const float* __restrict__ att_s, const float* __restrict__ att_d,
        float* __restrict__ as2, float* __restrict__ ad2){
    int n = blockIdx.x, t = threadIdx.x;
    float ps = 0.f, pd = 0.f;
    if (t < 40){
        float4 h = *(const float4*)(h2 + (size_t)n*F2 + t*4);
        float4 a = ((const float4*)att_s)[t];
        float4 d = ((const float4*)att_d)[t];
        ps = h.x*a.x + h.y*a.y + h.z*a.z + h.w*a.w;
        pd = h.x*d.x + h.y*d.y + h.z*d.z + h.w*d.w;
    }
    ps += __shfl_xor(ps,1); ps += __shfl_xor(ps,2); ps += __shfl_xor(ps,4);
    pd += __shfl_xor(pd,1); pd += __shfl_xor(pd,2); pd += __shfl_xor(pd,4);
    if (t < 40 && (t & 7) == 0){
        as2[n*NH2 + (t>>3)] = ps;
        ad2[n*NH2 + (t>>3)] = pd;
    }
}

// ------- layer-2 softmax + aggregation + head-mean + b2 ----------------------
__global__ __launch_bounds__(256) void k_agg2(const float* __restrict__ h2,
        const float* __restrict__ as2, const float* __restrict__ ad2,
        const int* __restrict__ row_start, const int* __restrict__ csr_src,
        const float* __restrict__ b2, float* __restrict__ x2){
    int n = blockIdx.x, t = threadIdx.x;
    __shared__ float ad_s[NH2], den_s[NH2], sacc[F2];
    int e0 = row_start[n], e1 = row_start[n+1];
    if (t < NH2) ad_s[t] = ad2[n*NH2 + t];
    __syncthreads();
    if (t < NH2){
        float d = 0.f;
        for (int e=e0;e<e1;e++){
            int s = csr_src[e];
            d += expf(lrelu(as2[s*NH2 + t] + ad_s[t]));
        }
        den_s[t] = d;
    }
    __syncthreads();
    if (t < F2){
        int h = t >> 5;
        float adh  = ad_s[h];
        float dinv = 1.f/den_s[h];
        float acc = 0.f;
        for (int e=e0;e<e1;e++){
            int s = csr_src[e];
            float w = expf(lrelu(as2[s*NH2 + h] + adh)) * dinv;
            acc += w * h2[(size_t)s*F2 + t];
        }
        sacc[t] = acc;
    }
    __syncthreads();
    if (t < OUT_F){
        float v = (sacc[t] + sacc[t+32] + sacc[t+64] + sacc[t+96] + sacc[t+128]) * 0.2f + b2[t];
        x2[n*OUT_F + t] = v;
    }
}

// ---------------- bond scores + softmax over 64 bonds ----------------
__global__ __launch_bounds__(64) void k_bond(const float* __restrict__ x2,
        const int* __restrict__ lefts, const int* __restrict__ rights,
        float* __restrict__ out){
    int b = threadIdx.x;
    int L = lefts[b], R = rights[b];
    float s = 0.f;
    #pragma unroll
    for (int c=0;c<OUT_F;c+=4){
        float4 l4 = *(const float4*)(x2 + (size_t)L*OUT_F + c);
        float4 r4 = *(const float4*)(x2 + (size_t)R*OUT_F + c);
        s += l4.x+l4.y+l4.z+l4.w + r4.x+r4.y+r4.z+r4.w;
    }
    float m = s;
    #pragma unroll
    for (int off=1; off<64; off<<=1) m = fmaxf(m, __shfl_xor(m, off));
    float e = expf(s - m);
    float sum = e;
    #pragma unroll
    for (int off=1; off<64; off<<=1) sum += __shfl_xor(sum, off);
    out[b] = e / sum;
}

extern "C" void kernel_launch(void* const* d_in, const int* in_sizes, int n_in,
                              void* d_out, int out_size, void* d_ws, size_t ws_size,
                              hipStream_t stream){
    const float* x      = (const float*)d_in[0];
    const int*   ei     = (const int*)  d_in[1];
    const int*   lefts  = (const int*)  d_in[2];
    const int*   rights = (const int*)  d_in[3];
    const float* W1     = (const float*)d_in[4];
    const float* att_s1 = (const float*)d_in[5];
    const float* att_d1 = (const float*)d_in[6];
    const float* b1     = (const float*)d_in[7];
    const float* W2     = (const float*)d_in[8];
    const float* att_s2 = (const float*)d_in[9];
    const float* att_d2 = (const float*)d_in[10];
    const float* b2     = (const float*)d_in[11];
    float* out = (float*)d_out;

    // fixed layout ~161 MB (< proven 167 MB workspace floor)
    char* ws = (char*)d_ws;
    size_t off = 0;
    auto alloc = [&](size_t bytes) -> void* {
        void* p = ws + off;
        off += (bytes + 255) & ~(size_t)255;
        return p;
    };
    unsigned short* x1fh = (unsigned short*)alloc((size_t)N_NODES*F1*2);   // 67.1 MB frag
    unsigned short* x1fl = (unsigned short*)alloc((size_t)N_NODES*F1*2);   // 67.1 MB
    float* part   = (float*)alloc((size_t)KS2*N_NODES*F2*4);               // 10.5 MB
    float* h2     = (float*)alloc((size_t)N_NODES*F2*4);
    float* as1    = (float*)alloc((size_t)N_NODES*NH1*4);
    float* ad1    = (float*)alloc((size_t)N_NODES*NH1*4);
    float* as2    = (float*)alloc((size_t)N_NODES*NH2*4);
    float* ad2    = (float*)alloc((size_t)N_NODES*NH2*4);
    float* x2     = (float*)alloc((size_t)N_NODES*OUT_F*4);
    float* vsT    = (float*)alloc((size_t)IN_F*NH1*4);
    float* vdT    = (float*)alloc((size_t)IN_F*NH1*4);
    unsigned short* w1fh = (unsigned short*)alloc((size_t)F1*IN_F*2);
    unsigned short* w1fl = (unsigned short*)alloc((size_t)F1*IN_F*2);
    unsigned short* w2fh = (unsigned short*)alloc((size_t)128*10*512*2);
    unsigned short* w2fl = (unsigned short*)alloc((size_t)128*10*512*2);
    int* counts    = (int*)alloc((size_t)N_NODES*4);
    int* row_start = (int*)alloc((size_t)(N_NODES+1)*4);
    int* cursor    = (int*)alloc((size_t)N_NODES*4);
    int* csr_src   = (int*)alloc((size_t)E_TOT*4);

    // CSR by destination
    k_init_counts<<<32, 256, 0, stream>>>(counts);
    k_count<<<192, 256, 0, stream>>>(ei, counts);
    k_scan<<<1, 1024, 0, stream>>>(counts, row_start, cursor);
    k_fill<<<224, 256, 0, stream>>>(ei, cursor, csr_src);

    // fragment-order split-bf16 weight packs (direct from fp32)
    k_packw1d<<<65536/256, 256, 0, stream>>>(W1, w1fh, w1fl);
    k_packw2d<<<81920/256, 256, 0, stream>>>(W2, w2fh, w2fl);

    // alpha dots (once, from x); denominators fused into k_l1f
    k_attvec<<<NH1, 128, 0, stream>>>(W1, att_s1, att_d1, vsT, vdT);
    k_alpha1x<<<N_NODES, 128, 0, stream>>>(x, vsT, vdT, as1, ad1);

    // fused layer 1 (single dispatch): agg + per-head MFMA + ELU -> x1 frags
    k_l1f<<<dim3(N_NODES/16, NH1/4), 256, 0, stream>>>(
        x, as1, ad1, row_start, csr_src, w1fh, w1fl, b1, x1fh, x1fl);

    // layer-2 projection (single dispatch) + reduce
    k_gemm2c<<<dim3(256, KS2), 256, 0, stream>>>(x1fh, x1fl, w2fh, w2fl, part);
    k_reduce<<<N_NODES*F2/4/256, 256, 0, stream>>>(part, h2);

    k_alpha2<<<N_NODES, 64, 0, stream>>>(h2, att_s2, att_d2, as2, ad2);
    k_agg2<<<N_NODES, 256, 0, stream>>>(h2, as2, ad2, row_start, csr_src, b2, x2);

    k_bond<<<1, 64, 0, stream>>>(x2, lefts, rights, out);
}

// Round 17
// 365.655 us; speedup vs baseline: 1.4155x; 1.4155x over previous
//
#include <hip/hip_runtime.h>
#include <hip/hip_bf16.h>
#include <math.h>

#define N_NODES  8192
#define N_EDGES  49152
#define E_TOT    57344   // edges + self-loops
#define IN_F     128
#define HID      64
#define NH1      64
#define NH2      5
#define OUT_F    32
#define F1       4096    // NH1*HID
#define F2       160     // NH2*OUT_F
#define N_BONDS  64
#define ET       16      // aggx edge-tile
#define KS2      2       // gemm2 k-split (partial buffers)
#define CH       16      // heads per chunk (4 chunks)

typedef short bf16x8 __attribute__((ext_vector_type(8)));
typedef float f32x4  __attribute__((ext_vector_type(4)));

__device__ __forceinline__ float lrelu(float x){ return x > 0.f ? x : 0.2f*x; }

__device__ __forceinline__ unsigned short bf16_rne(float f){
    unsigned u = __float_as_uint(f);
    unsigned r = u + 0x7FFF + ((u >> 16) & 1);
    return (unsigned short)(r >> 16);
}
__device__ __forceinline__ float bf16f(unsigned short h){
    return __uint_as_float((unsigned)h << 16);
}

// ---------------- CSR build (sort edges by dst) ----------------
__global__ void k_init_counts(int* counts){
    int i = blockIdx.x*256 + threadIdx.x;
    if (i < N_NODES) counts[i] = 1;   // self-loop
}
__global__ void k_count(const int* __restrict__ ei, int* counts){
    int i = blockIdx.x*256 + threadIdx.x;
    if (i < N_EDGES) atomicAdd(&counts[ei[N_EDGES + i]], 1);
}
__global__ __launch_bounds__(1024) void k_scan(const int* __restrict__ counts,
                                               int* __restrict__ row_start,
                                               int* __restrict__ cursor){
    __shared__ int sd[1024];
    int t = threadIdx.x;
    int v[8]; int sum = 0;
    #pragma unroll
    for (int i=0;i<8;i++){ v[i] = counts[t*8+i]; sum += v[i]; }
    sd[t] = sum; __syncthreads();
    for (int off=1; off<1024; off<<=1){
        int vv = (t >= off) ? sd[t-off] : 0;
        __syncthreads();
        sd[t] += vv;
        __syncthreads();
    }
    int run = sd[t] - sum;  // exclusive prefix
    #pragma unroll
    for (int i=0;i<8;i++){ row_start[t*8+i] = run; cursor[t*8+i] = run; run += v[i]; }
    if (t == 1023) row_start[N_NODES] = run;
}
__global__ void k_fill(const int* __restrict__ ei, int* cursor, int* __restrict__ csr_src){
    int i = blockIdx.x*256 + threadIdx.x;
    if (i >= E_TOT) return;
    int s, d;
    if (i < N_EDGES){ s = ei[i]; d = ei[N_EDGES + i]; }
    else { s = i - N_EDGES; d = s; }
    int pos = atomicAdd(&cursor[d], 1);
    csr_src[pos] = s;
}

// ---- pack W1 fp32 -> split-bf16 B-fragment order: [hg][ks][ct][lane][8] ----
__global__ void k_packw1d(const float* __restrict__ W1,
                          unsigned short* __restrict__ fh, unsigned short* __restrict__ fl){
    int g = blockIdx.x*256 + threadIdx.x;            // 64*4*4*64 = 65536 groups
    int lane = g & 63, ct = (g >> 6) & 3, ks = (g >> 8) & 3, hg = g >> 10;
    int col = hg*64 + ct*16 + (lane & 15);
    int k = ks*32 + (lane >> 4)*8;
    const float* src = W1 + (size_t)col*IN_F + k;
    bf16x8 hv, lv;
    #pragma unroll
    for (int j=0;j<8;j++){
        float f = src[j];
        unsigned short hb = bf16_rne(f);
        hv[j] = (short)hb;
        lv[j] = (short)bf16_rne(f - bf16f(hb));
    }
    *(bf16x8*)(fh + (size_t)g*8) = hv;
    *(bf16x8*)(fl + (size_t)g*8) = lv;
}

// ---- pack W2 fp32 -> split-bf16 B-fragment order: [kc][ni][lane][8] ----
__global__ void k_packw2d(const float* __restrict__ W2,
                          unsigned short* __restrict__ fh, unsigned short* __restrict__ fl){
    int g = blockIdx.x*256 + threadIdx.x;            // 128*10*64 = 81920 groups
    int lane = g & 63, ni = (g >> 6) % 10, kc = g / 640;
    int n = ni*16 + (lane & 15);
    int k = kc*32 + (lane >> 4)*8;
    const float* src = W2 + (size_t)n*F1 + k;
    bf16x8 hv, lv;
    #pragma unroll
    for (int j=0;j<8;j++){
        float f = src[j];
        unsigned short hb = bf16_rne(f);
        hv[j] = (short)hb;
        lv[j] = (short)bf16_rne(f - bf16f(hb));
    }
    *(bf16x8*)(fh + (size_t)g*8) = hv;
    *(bf16x8*)(fl + (size_t)g*8) = lv;
}

// ------- attention vectors: vsT[k][h] = sum_c a_s[h,c] * W1[h*64+c, k] -------
__global__ __launch_bounds__(128) void k_attvec(const float* __restrict__ W1,
        const float* __restrict__ a_s, const float* __restrict__ a_d,
        float* __restrict__ vsT, float* __restrict__ vdT){
    int h = blockIdx.x, k = threadIdx.x;
    float s = 0.f, d = 0.f;
    for (int c = 0; c < HID; c++){
        float w = W1[(size_t)(h*HID + c)*IN_F + k];
        s += a_s[h*HID + c] * w;
        d += a_d[h*HID + c] * w;
    }
    vsT[k*NH1 + h] = s;
    vdT[k*NH1 + h] = d;
}

// ---------- alpha dots from x: as1[n,h] = x[n,:] . vsT[:,h] ------------------
__global__ __launch_bounds__(128) void k_alpha1x(const float* __restrict__ x,
        const float* __restrict__ vsT, const float* __restrict__ vdT,
        float* __restrict__ as1, float* __restrict__ ad1){
    int n = blockIdx.x, t = threadIdx.x;
    __shared__ float xs[IN_F];
    xs[t] = x[(size_t)n*IN_F + t];
    __syncthreads();
    if (t < NH1){
        float s = 0.f, d = 0.f;
        for (int k = 0; k < IN_F; k++){
            float xv = xs[k];
            s += xv * vsT[k*NH1 + t];
            d += xv * vdT[k*NH1 + t];
        }
        as1[n*NH1 + t] = s;
        ad1[n*NH1 + t] = d;
    }
}

// ------- x-space aggregation, CH heads, denom fused (R13 structure) ----------
// Block per dst node, 256 thr: h = t>>4, f0 = (t&15)*8. Output: bf16 hi-plane
// only (precision budget: measured absmax 0.0 with full split -> >=3 orders
// of margin). CONTIGUOUS writes: each (h,n) emits a 256B run.
__global__ __launch_bounds__(256) void k_aggx2(const float* __restrict__ x,
        const float* __restrict__ as1, const float* __restrict__ ad1,
        const int* __restrict__ row_start, const int* __restrict__ csr_src,
        unsigned short* __restrict__ txhi, int h0){
    int n = blockIdx.x, t = threadIdx.x;
    __shared__ float ad_s[CH], dv_s[CH];
    __shared__ float wt[ET][CH];
    __shared__ int   st[ET];
    __shared__ float xs[ET][IN_F];
    int e0 = row_start[n], e1 = row_start[n+1];
    if (t < CH) ad_s[t] = ad1[n*NH1 + h0 + t];
    int h = t >> 4, f0 = (t & 15)*8;
    float acc[8] = {};
    float D = 0.f;
    for (int eb = e0; eb < e1; eb += ET){
        int ne = min(ET, e1 - eb);
        if (t < ne) st[t] = csr_src[eb + t];
        __syncthreads();
        for (int idx = t; idx < ne*32; idx += 256){
            int e = idx >> 5, f4 = idx & 31;
            *(float4*)&xs[e][f4*4] = *(const float4*)(x + (size_t)st[e]*IN_F + f4*4);
        }
        for (int idx = t; idx < ne*CH; idx += 256){
            int e = idx >> 4, hh = idx & (CH-1);
            wt[e][hh] = expf(lrelu(as1[st[e]*NH1 + h0 + hh] + ad_s[hh]));
        }
        __syncthreads();
        for (int e = 0; e < ne; e++){
            float w = wt[e][h];
            D += w;
            float4 v0 = *(const float4*)&xs[e][f0];
            float4 v1 = *(const float4*)&xs[e][f0+4];
            acc[0] += w*v0.x; acc[1] += w*v0.y; acc[2] += w*v0.z; acc[3] += w*v0.w;
            acc[4] += w*v1.x; acc[5] += w*v1.y; acc[6] += w*v1.z; acc[7] += w*v1.w;
        }
        __syncthreads();
    }
    float dinv = 1.f / D;
    bf16x8 hv;
    #pragma unroll
    for (int j=0;j<8;j++) hv[j] = (short)bf16_rne(acc[j] * dinv);
    size_t o = ((size_t)h*N_NODES + n)*IN_F + f0;
    *(bf16x8*)(txhi + o) = hv;
}

// ------- per-head GEMM (MFMA: A bf16 x B split-bf16) + bias/ELU --------------
// grid (64, CH); 4 waves 2x2; wave tile 64 rows x 32 cols, K=128.
// A from row-major tx (hi only), B from frag-packed w1 (1KB streams).
// Output x1 bf16 hi-plane in gemm2 A-fragment order.
__global__ __launch_bounds__(256) void k_gemm1h(const unsigned short* __restrict__ txhi,
        const unsigned short* __restrict__ w1fh,
        const unsigned short* __restrict__ w1fl,
        const float* __restrict__ b1,
        unsigned short* __restrict__ x1fh, int h0){
    __shared__ unsigned short hs[4][64][36];
    int wave = threadIdx.x >> 6, lane = threadIdx.x & 63;
    int wm = wave & 1, wn = wave >> 1;
    int hc = blockIdx.y;
    int hg = h0 + hc;
    int m0 = blockIdx.x * 128;
    int q = lane >> 4, l16 = lane & 15;
    const unsigned short* Ah = txhi + (size_t)hc*N_NODES*IN_F;
    f32x4 acc[4][2] = {};
    #pragma unroll
    for (int ks = 0; ks < 4; ks++){
        int kb = ks*32 + q*8;
        bf16x8 ah[4], bh[2], bl[2];
        #pragma unroll
        for (int mi=0;mi<4;mi++){
            size_t r = (size_t)(m0 + wm*64 + mi*16 + l16)*IN_F + kb;
            ah[mi] = *(const bf16x8*)(Ah + r);
        }
        #pragma unroll
        for (int ni=0;ni<2;ni++){
            size_t r = (((size_t)hg*4 + ks)*4 + wn*2 + ni)*512 + lane*8;
            bh[ni] = *(const bf16x8*)(w1fh + r);
            bl[ni] = *(const bf16x8*)(w1fl + r);
        }
        #pragma unroll
        for (int mi=0;mi<4;mi++)
            #pragma unroll
            for (int ni=0;ni<2;ni++){
                acc[mi][ni] = __builtin_amdgcn_mfma_f32_16x16x32_bf16(ah[mi], bh[ni], acc[mi][ni], 0,0,0);
                acc[mi][ni] = __builtin_amdgcn_mfma_f32_16x16x32_bf16(ah[mi], bl[ni], acc[mi][ni], 0,0,0);
            }
    }
    // bias + ELU -> per-wave LDS tile [64 rows][32 cols]
    #pragma unroll
    for (int mi=0;mi<4;mi++)
        #pragma unroll
        for (int ni=0;ni<2;ni++){
            int c = wn*32 + ni*16 + l16;
            float b = b1[hg*64 + c];
            #pragma unroll
            for (int i=0;i<4;i++){
                float v = acc[mi][ni][i] + b;
                float o = v > 0.f ? v : expm1f(v);
                int rr = mi*16 + q*4 + i;
                hs[wave][rr][ni*16 + l16] = bf16_rne(o);
            }
        }
    __syncthreads();
    // LDS -> fragment-order write (gemm2 A-frag); each 16B lane-write lands
    // in a 1KB contiguous run per (mtile, ksg).
    int ksg = hc*2 + wn;
    #pragma unroll
    for (int mi=0;mi<4;mi++){
        int mtile = blockIdx.x*8 + wm*4 + mi;
        bf16x8 fh = *(const bf16x8*)&hs[wave][mi*16 + l16][q*8];
        size_t o = ((size_t)mtile*32 + ksg)*512 + lane*8;
        *(bf16x8*)(x1fh + o) = fh;
    }
}

// ------- GEMM2 chunk (MFMA: A bf16 x B split-bf16, all-fragment-packed) ------
// grid (256, KS2); block 256 = 4 waves (2 m-tiles x 2 n-halves of 80).
// Fully unrolled k-loop; all loads lane-contiguous 1KB streams.
__global__ __launch_bounds__(256) void k_gemm2c(
        const unsigned short* __restrict__ x1fh,
        const unsigned short* __restrict__ w2fh, const unsigned short* __restrict__ w2fl,
        float* __restrict__ P, int kc0, int first){
    int wave = threadIdx.x >> 6, lane = threadIdx.x & 63;
    int wm = wave & 1, wn = wave >> 1;
    int q = lane >> 4, l16 = lane & 15;
    int mtile = blockIdx.x*2 + wm;
    int ks2 = blockIdx.y;
    int ks0 = ks2 * 16;
    const unsigned short* Ah = x1fh + ((size_t)mtile*32 + ks0)*512 + lane*8;
    const unsigned short* Bh = w2fh + ((size_t)(kc0 + ks0)*10 + wn*5)*512 + lane*8;
    const unsigned short* Bl = w2fl + ((size_t)(kc0 + ks0)*10 + wn*5)*512 + lane*8;
    f32x4 acc[5] = {};
    #pragma unroll
    for (int t = 0; t < 16; t++){
        bf16x8 ah = *(const bf16x8*)(Ah + (size_t)t*512);
        bf16x8 bh[5], bl[5];
        #pragma unroll
        for (int ni=0;ni<5;ni++){
            bh[ni] = *(const bf16x8*)(Bh + (size_t)(t*10 + ni)*512);
            bl[ni] = *(const bf16x8*)(Bl + (size_t)(t*10 + ni)*512);
        }
        #pragma unroll
        for (int ni=0;ni<5;ni++){
            acc[ni] = __builtin_amdgcn_mfma_f32_16x16x32_bf16(ah, bh[ni], acc[ni], 0,0,0);
            acc[ni] = __builtin_amdgcn_mfma_f32_16x16x32_bf16(ah, bl[ni], acc[ni], 0,0,0);
        }
    }
    float* outp = P + (size_t)ks2 * N_NODES * F2;
    if (first){
        #pragma unroll
        for (int ni=0;ni<5;ni++)
            #pragma unroll
            for (int i=0;i<4;i++)
                outp[(size_t)(mtile*16 + q*4 + i)*F2 + wn*80 + ni*16 + l16] = acc[ni][i];
    } else {
        #pragma unroll
        for (int ni=0;ni<5;ni++)
            #pragma unroll
            for (int i=0;i<4;i++){
                size_t idx = (size_t)(mtile*16 + q*4 + i)*F2 + wn*80 + ni*16 + l16;
                outp[idx] += acc[ni][i];
            }
    }
}

// ---------------- reduce KS2 partials -> h2 ----------------
__global__ __launch_bounds__(256) void k_reduce(const float* __restrict__ P,
                                                float* __restrict__ h2){
    const int NV = N_NODES*F2/4;
    int i = blockIdx.x*256 + threadIdx.x;
    float4 a = ((const float4*)P)[i];
    #pragma unroll
    for (int kb = 1; kb < KS2; kb++){
        float4 b = ((const float4*)P)[(size_t)kb*NV + i];
        a.x += b.x; a.y += b.y; a.z += b.z; a.w += b.w;
    }
    ((float4*)h2)[i] = a;
}

// ---------------- attention dots, layer 2 ----------------
__global__ __launch_bounds__(64) void k_alpha2(const float* __restrict__ h2,
        const float* __restrict__ att_s, const float* __restrict__ att_d,
        float* __restrict__ as2, float* __restrict__ ad2){
    int n = blockIdx.x, t = threadIdx.x;
    float ps = 0.f, pd = 0.f;
    if (t < 40){
        float4 h = *(const float4*)(h2 + (size_t)n*F2 + t*4);
        float4 a = ((const float4*)att_s)[t];
        float4 d = ((const float4*)att_d)[t];
        ps = h.x*a.x + h.y*a.y + h.z*a.z + h.w*a.w;
        pd = h.x*d.x + h.y*d.y + h.z*d.z + h.w*d.w;
    }
    ps += __shfl_xor(ps,1); ps += __shfl_xor(ps,2); ps += __shfl_xor(ps,4);
    pd += __shfl_xor(pd,1); pd += __shfl_xor(pd,2); pd += __shfl_xor(pd,4);
    if (t < 40 && (t & 7) == 0){
        as2[n*NH2 + (t>>3)] = ps;
        ad2[n*NH2 + (t>>3)] = pd;
    }
}

// ------- layer-2 softmax + aggregation + head-mean + b2 ----------------------
__global__ __launch_bounds__(256) void k_agg2(const float* __restrict__ h2,
        const float* __restrict__ as2, const float* __restrict__ ad2,
        const int* __restrict__ row_start, const int* __restrict__ csr_src,
        const float* __restrict__ b2, float* __restrict__ x2){
    int n = blockIdx.x, t = threadIdx.x;
    __shared__ float ad_s[NH2], den_s[NH2], sacc[F2];
    int e0 = row_start[n], e1 = row_start[n+1];
    if (t < NH2) ad_s[t] = ad2[n*NH2 + t];
    __syncthreads();
    if (t < NH2){
        float d = 0.f;
        for (int e=e0;e<e1;e++){
            int s = csr_src[e];
            d += expf(lrelu(as2[s*NH2 + t] + ad_s[t]));
        }
        den_s[t] = d;
    }
    __syncthreads();
    if (t < F2){
        int h = t >> 5;
        float adh  = ad_s[h];
        float dinv = 1.f/den_s[h];
        float acc = 0.f;
        for (int e=e0;e<e1;e++){
            int s = csr_src[e];
            float w = expf(lrelu(as2[s*NH2 + h] + adh)) * dinv;
            acc += w * h2[(size_t)s*F2 + t];
        }
        sacc[t] = acc;
    }
    __syncthreads();
    if (t < OUT_F){
        float v = (sacc[t] + sacc[t+32] + sacc[t+64] + sacc[t+96] + sacc[t+128]) * 0.2f + b2[t];
        x2[n*OUT_F + t] = v;
    }
}

// ---------------- bond scores + softmax over 64 bonds ----------------
__global__ __launch_bounds__(64) void k_bond(const float* __restrict__ x2,
        const int* __restrict__ lefts, const int* __restrict__ rights,
        float* __restrict__ out){
    int b = threadIdx.x;
    int L = lefts[b], R = rights[b];
    float s = 0.f;
    #pragma unroll
    for (int c=0;c<OUT_F;c+=4){
        float4 l4 = *(const float4*)(x2 + (size_t)L*OUT_F + c);
        float4 r4 = *(const float4*)(x2 + (size_t)R*OUT_F + c);
        s += l4.x+l4.y+l4.z+l4.w + r4.x+r4.y+r4.z+r4.w;
    }
    float m = s;
    #pragma unroll
    for (int off=1; off<64; off<<=1) m = fmaxf(m, __shfl_xor(m, off));
    float e = expf(s - m);
    float sum = e;
    #pragma unroll
    for (int off=1; off<64; off<<=1) sum += __shfl_xor(sum, off);
    out[b] = e / sum;
}

extern "C" void kernel_launch(void* const* d_in, const int* in_sizes, int n_in,
                              void* d_out, int out_size, void* d_ws, size_t ws_size,
                              hipStream_t stream){
    const float* x      = (const float*)d_in[0];
    const int*   ei     = (const int*)  d_in[1];
    const int*   lefts  = (const int*)  d_in[2];
    const int*   rights = (const int*)  d_in[3];
    const float* W1     = (const float*)d_in[4];
    const float* att_s1 = (const float*)d_in[5];
    const float* att_d1 = (const float*)d_in[6];
    const float* b1     = (const float*)d_in[7];
    const float* W2     = (const float*)d_in[8];
    const float* att_s2 = (const float*)d_in[9];
    const float* att_d2 = (const float*)d_in[10];
    const float* b2     = (const float*)d_in[11];
    float* out = (float*)d_out;

    // fixed layout ~90 MB (< proven 167 MB workspace floor)
    char* ws = (char*)d_ws;
    size_t off = 0;
    auto alloc = [&](size_t bytes) -> void* {
        void* p = ws + off;
        off += (bytes + 255) & ~(size_t)255;
        return p;
    };
    unsigned short* txhi = (unsigned short*)alloc((size_t)CH*N_NODES*IN_F*2);  // 33.5 MB
    unsigned short* x1fh = (unsigned short*)alloc((size_t)N_NODES*CH*HID*2);   // 16.8 MB frag
    float* part   = (float*)alloc((size_t)KS2*N_NODES*F2*4);                   // 10.5 MB
    float* h2     = (float*)alloc((size_t)N_NODES*F2*4);
    float* as1    = (float*)alloc((size_t)N_NODES*NH1*4);
    float* ad1    = (float*)alloc((size_t)N_NODES*NH1*4);
    float* as2    = (float*)alloc((size_t)N_NODES*NH2*4);
    float* ad2    = (float*)alloc((size_t)N_NODES*NH2*4);
    float* x2     = (float*)alloc((size_t)N_NODES*OUT_F*4);
    float* vsT    = (float*)alloc((size_t)IN_F*NH1*4);
    float* vdT    = (float*)alloc((size_t)IN_F*NH1*4);
    unsigned short* w1fh = (unsigned short*)alloc((size_t)F1*IN_F*2);
    unsigned short* w1fl = (unsigned short*)alloc((size_t)F1*IN_F*2);
    unsigned short* w2fh = (unsigned short*)alloc((size_t)128*10*512*2);
    unsigned short* w2fl = (unsigned short*)alloc((size_t)128*10*512*2);
    int* counts    = (int*)alloc((size_t)N_NODES*4);
    int* row_start = (int*)alloc((size_t)(N_NODES+1)*4);
    int* cursor    = (int*)alloc((size_t)N_NODES*4);
    int* csr_src   = (int*)alloc((size_t)E_TOT*4);

    // CSR by destination
    k_init_counts<<<32, 256, 0, stream>>>(counts);
    k_count<<<192, 256, 0, stream>>>(ei, counts);
    k_scan<<<1, 1024, 0, stream>>>(counts, row_start, cursor);
    k_fill<<<224, 256, 0, stream>>>(ei, cursor, csr_src);

    // fragment-order split-bf16 weight packs (direct from fp32)
    k_packw1d<<<65536/256, 256, 0, stream>>>(W1, w1fh, w1fl);
    k_packw2d<<<81920/256, 256, 0, stream>>>(W2, w2fh, w2fl);

    // alpha dots (once, from x); denominators fused into k_aggx2
    k_attvec<<<NH1, 128, 0, stream>>>(W1, att_s1, att_d1, vsT, vdT);
    k_alpha1x<<<N_NODES, 128, 0, stream>>>(x, vsT, vdT, as1, ad1);

    for (int c = 0; c < NH1/CH; c++){
        int h0 = c * CH;
        k_aggx2<<<N_NODES, 256, 0, stream>>>(
            x, as1, ad1, row_start, csr_src, txhi, h0);
        k_gemm1h<<<dim3(64, CH), 256, 0, stream>>>(
            txhi, w1fh, w1fl, b1, x1fh, h0);
        k_gemm2c<<<dim3(256, KS2), 256, 0, stream>>>(
            x1fh, w2fh, w2fl, part, c*32, c == 0 ? 1 : 0);
    }

    k_reduce<<<N_NODES*F2/4/256, 256, 0, stream>>>(part, h2);
    k_alpha2<<<N_NODES, 64, 0, stream>>>(h2, att_s2, att_d2, as2, ad2);
    k_agg2<<<N_NODES, 256, 0, stream>>>(h2, as2, ad2, row_start, csr_src, b2, x2);

    k_bond<<<1, 64, 0, stream>>>(x2, lefts, rights, out);
}

// Round 18
// 335.937 us; speedup vs baseline: 1.5407x; 1.0885x over previous
//
#include <hip/hip_runtime.h>
#include <hip/hip_bf16.h>
#include <math.h>

#define N_NODES  8192
#define N_EDGES  49152
#define E_TOT    57344   // edges + self-loops
#define IN_F     128
#define HID      64
#define NH1      64
#define NH2      5
#define OUT_F    32
#define F1       4096    // NH1*HID
#define F2       160     // NH2*OUT_F
#define N_BONDS  64
#define ET       16      // aggx edge-tile
#define KS2      2       // gemm2 k-split (partial buffers)

typedef short bf16x8 __attribute__((ext_vector_type(8)));
typedef float f32x4  __attribute__((ext_vector_type(4)));

__device__ __forceinline__ float lrelu(float x){ return x > 0.f ? x : 0.2f*x; }

__device__ __forceinline__ unsigned short bf16_rne(float f){
    unsigned u = __float_as_uint(f);
    unsigned r = u + 0x7FFF + ((u >> 16) & 1);
    return (unsigned short)(r >> 16);
}
__device__ __forceinline__ float bf16f(unsigned short h){
    return __uint_as_float((unsigned)h << 16);
}

// ---------------- CSR build (sort edges by dst) ----------------
__global__ void k_init_counts(int* counts){
    int i = blockIdx.x*256 + threadIdx.x;
    if (i < N_NODES) counts[i] = 1;   // self-loop
}
__global__ void k_count(const int* __restrict__ ei, int* counts){
    int i = blockIdx.x*256 + threadIdx.x;
    if (i < N_EDGES) atomicAdd(&counts[ei[N_EDGES + i]], 1);
}
__global__ __launch_bounds__(1024) void k_scan(const int* __restrict__ counts,
                                               int* __restrict__ row_start,
                                               int* __restrict__ cursor){
    __shared__ int sd[1024];
    int t = threadIdx.x;
    int v[8]; int sum = 0;
    #pragma unroll
    for (int i=0;i<8;i++){ v[i] = counts[t*8+i]; sum += v[i]; }
    sd[t] = sum; __syncthreads();
    for (int off=1; off<1024; off<<=1){
        int vv = (t >= off) ? sd[t-off] : 0;
        __syncthreads();
        sd[t] += vv;
        __syncthreads();
    }
    int run = sd[t] - sum;  // exclusive prefix
    #pragma unroll
    for (int i=0;i<8;i++){ row_start[t*8+i] = run; cursor[t*8+i] = run; run += v[i]; }
    if (t == 1023) row_start[N_NODES] = run;
}
__global__ void k_fill(const int* __restrict__ ei, int* cursor, int* __restrict__ csr_src){
    int i = blockIdx.x*256 + threadIdx.x;
    if (i >= E_TOT) return;
    int s, d;
    if (i < N_EDGES){ s = ei[i]; d = ei[N_EDGES + i]; }
    else { s = i - N_EDGES; d = s; }
    int pos = atomicAdd(&cursor[d], 1);
    csr_src[pos] = s;
}

// ---- pack W1 fp32 -> split-bf16 B-fragment order: [hg][ks][ct][lane][8] ----
__global__ void k_packw1d(const float* __restrict__ W1,
                          unsigned short* __restrict__ fh, unsigned short* __restrict__ fl){
    int g = blockIdx.x*256 + threadIdx.x;            // 64*4*4*64 = 65536 groups
    int lane = g & 63, ct = (g >> 6) & 3, ks = (g >> 8) & 3, hg = g >> 10;
    int col = hg*64 + ct*16 + (lane & 15);
    int k = ks*32 + (lane >> 4)*8;
    const float* src = W1 + (size_t)col*IN_F + k;
    bf16x8 hv, lv;
    #pragma unroll
    for (int j=0;j<8;j++){
        float f = src[j];
        unsigned short hb = bf16_rne(f);
        hv[j] = (short)hb;
        lv[j] = (short)bf16_rne(f - bf16f(hb));
    }
    *(bf16x8*)(fh + (size_t)g*8) = hv;
    *(bf16x8*)(fl + (size_t)g*8) = lv;
}

// ---- pack W2 fp32 -> split-bf16 B-fragment order: [kc][ni][lane][8] ----
__global__ void k_packw2d(const float* __restrict__ W2,
                          unsigned short* __restrict__ fh, unsigned short* __restrict__ fl){
    int g = blockIdx.x*256 + threadIdx.x;            // 128*10*64 = 81920 groups
    int lane = g & 63, ni = (g >> 6) % 10, kc = g / 640;
    int n = ni*16 + (lane & 15);
    int k = kc*32 + (lane >> 4)*8;
    const float* src = W2 + (size_t)n*F1 + k;
    bf16x8 hv, lv;
    #pragma unroll
    for (int j=0;j<8;j++){
        float f = src[j];
        unsigned short hb = bf16_rne(f);
        hv[j] = (short)hb;
        lv[j] = (short)bf16_rne(f - bf16f(hb));
    }
    *(bf16x8*)(fh + (size_t)g*8) = hv;
    *(bf16x8*)(fl + (size_t)g*8) = lv;
}

// ------- attention vectors: vsT[k][h] = sum_c a_s[h,c] * W1[h*64+c, k] -------
__global__ __launch_bounds__(128) void k_attvec(const float* __restrict__ W1,
        const float* __restrict__ a_s, const float* __restrict__ a_d,
        float* __restrict__ vsT, float* __restrict__ vdT){
    int h = blockIdx.x, k = threadIdx.x;
    float s = 0.f, d = 0.f;
    for (int c = 0; c < HID; c++){
        float w = W1[(size_t)(h*HID + c)*IN_F + k];
        s += a_s[h*HID + c] * w;
        d += a_d[h*HID + c] * w;
    }
    vsT[k*NH1 + h] = s;
    vdT[k*NH1 + h] = d;
}

// ---------- alpha dots from x: as1[n,h] = x[n,:] . vsT[:,h] ------------------
__global__ __launch_bounds__(128) void k_alpha1x(const float* __restrict__ x,
        const float* __restrict__ vsT, const float* __restrict__ vdT,
        float* __restrict__ as1, float* __restrict__ ad1){
    int n = blockIdx.x, t = threadIdx.x;
    __shared__ float xs[IN_F];
    xs[t] = x[(size_t)n*IN_F + t];
    __syncthreads();
    if (t < NH1){
        float s = 0.f, d = 0.f;
        for (int k = 0; k < IN_F; k++){
            float xv = xs[k];
            s += xv * vsT[k*NH1 + t];
            d += xv * vdT[k*NH1 + t];
        }
        as1[n*NH1 + t] = s;
        ad1[n*NH1 + t] = d;
    }
}

// ------- x-space aggregation, ALL 64 heads, denom fused, single dispatch -----
// Block per dst node, 256 thr: head-quad hq = t>>4 (4 heads), f0 = (t&15)*8.
// Edge-tiles staged once (vs 4x in the chunked version). Per-head accumulation
// order identical to the chunked version -> bit-identical results.
// Output: bf16 hi-plane, contiguous 256B runs per (head, node).
__global__ __launch_bounds__(256) void k_aggx64(const float* __restrict__ x,
        const float* __restrict__ as1, const float* __restrict__ ad1,
        const int* __restrict__ row_start, const int* __restrict__ csr_src,
        unsigned short* __restrict__ txhi){
    int n = blockIdx.x, t = threadIdx.x;
    __shared__ float ad_s[NH1];
    __shared__ float wt[ET][NH1];   // 4 KB
    __shared__ int   st[ET];
    __shared__ float xs[ET][IN_F];  // 8 KB
    int e0 = row_start[n], e1 = row_start[n+1];
    if (t < NH1) ad_s[t] = ad1[n*NH1 + t];
    int hq = t >> 4, f0 = (t & 15)*8;
    float acc[4][8] = {};
    float D[4] = {0.f, 0.f, 0.f, 0.f};
    for (int eb = e0; eb < e1; eb += ET){
        int ne = min(ET, e1 - eb);
        if (t < ne) st[t] = csr_src[eb + t];
        __syncthreads();
        for (int idx = t; idx < ne*32; idx += 256){
            int e = idx >> 5, f4 = idx & 31;
            *(float4*)&xs[e][f4*4] = *(const float4*)(x + (size_t)st[e]*IN_F + f4*4);
        }
        for (int idx = t; idx < ne*NH1; idx += 256){
            int e = idx >> 6, hh = idx & 63;
            wt[e][hh] = expf(lrelu(as1[st[e]*NH1 + hh] + ad_s[hh]));
        }
        __syncthreads();
        for (int e = 0; e < ne; e++){
            float4 v0 = *(const float4*)&xs[e][f0];
            float4 v1 = *(const float4*)&xs[e][f0+4];
            float xv[8] = {v0.x,v0.y,v0.z,v0.w,v1.x,v1.y,v1.z,v1.w};
            #pragma unroll
            for (int c=0;c<4;c++){
                float w = wt[e][hq*4 + c];
                D[c] += w;
                #pragma unroll
                for (int j=0;j<8;j++) acc[c][j] += w*xv[j];
            }
        }
        __syncthreads();
    }
    #pragma unroll
    for (int c=0;c<4;c++){
        float dinv = 1.f / D[c];
        bf16x8 hv;
        #pragma unroll
        for (int j=0;j<8;j++) hv[j] = (short)bf16_rne(acc[c][j] * dinv);
        size_t o = ((size_t)(hq*4 + c)*N_NODES + n)*IN_F + f0;
        *(bf16x8*)(txhi + o) = hv;
    }
}

// ------- per-head GEMM (MFMA: A bf16 x B split-bf16) + bias/ELU --------------
// grid (64, 64); 4 waves 2x2; wave tile 64 rows x 32 cols, K=128.
// A from row-major tx (hi only), B from frag-packed w1 (1KB streams).
// Output x1 bf16 hi-plane in gemm2 A-fragment order.
__global__ __launch_bounds__(256) void k_gemm1h(const unsigned short* __restrict__ txhi,
        const unsigned short* __restrict__ w1fh,
        const unsigned short* __restrict__ w1fl,
        const float* __restrict__ b1,
        unsigned short* __restrict__ x1fh){
    __shared__ unsigned short hs[4][64][36];
    int wave = threadIdx.x >> 6, lane = threadIdx.x & 63;
    int wm = wave & 1, wn = wave >> 1;
    int hg = blockIdx.y;
    int m0 = blockIdx.x * 128;
    int q = lane >> 4, l16 = lane & 15;
    const unsigned short* Ah = txhi + (size_t)hg*N_NODES*IN_F;
    f32x4 acc[4][2] = {};
    #pragma unroll
    for (int ks = 0; ks < 4; ks++){
        int kb = ks*32 + q*8;
        bf16x8 ah[4], bh[2], bl[2];
        #pragma unroll
        for (int mi=0;mi<4;mi++){
            size_t r = (size_t)(m0 + wm*64 + mi*16 + l16)*IN_F + kb;
            ah[mi] = *(const bf16x8*)(Ah + r);
        }
        #pragma unroll
        for (int ni=0;ni<2;ni++){
            size_t r = (((size_t)hg*4 + ks)*4 + wn*2 + ni)*512 + lane*8;
            bh[ni] = *(const bf16x8*)(w1fh + r);
            bl[ni] = *(const bf16x8*)(w1fl + r);
        }
        #pragma unroll
        for (int mi=0;mi<4;mi++)
            #pragma unroll
            for (int ni=0;ni<2;ni++){
                acc[mi][ni] = __builtin_amdgcn_mfma_f32_16x16x32_bf16(ah[mi], bh[ni], acc[mi][ni], 0,0,0);
                acc[mi][ni] = __builtin_amdgcn_mfma_f32_16x16x32_bf16(ah[mi], bl[ni], acc[mi][ni], 0,0,0);
            }
    }
    // bias + ELU -> per-wave LDS tile [64 rows][32 cols]
    #pragma unroll
    for (int mi=0;mi<4;mi++)
        #pragma unroll
        for (int ni=0;ni<2;ni++){
            int c = wn*32 + ni*16 + l16;
            float b = b1[hg*64 + c];
            #pragma unroll
            for (int i=0;i<4;i++){
                float v = acc[mi][ni][i] + b;
                float o = v > 0.f ? v : expm1f(v);
                int rr = mi*16 + q*4 + i;
                hs[wave][rr][ni*16 + l16] = bf16_rne(o);
            }
        }
    __syncthreads();
    // LDS -> fragment-order write (gemm2 A-frag); each 16B lane-write lands
    // in a 1KB contiguous run per (mtile, ksg). ksg spans 0..127 (all heads).
    int ksg = hg*2 + wn;
    #pragma unroll
    for (int mi=0;mi<4;mi++){
        int mtile = blockIdx.x*8 + wm*4 + mi;
        bf16x8 fh = *(const bf16x8*)&hs[wave][mi*16 + l16][q*8];
        size_t o = ((size_t)mtile*128 + ksg)*512 + lane*8;
        *(bf16x8*)(x1fh + o) = fh;
    }
}

// ------- GEMM2 (MFMA: A bf16 x B split-bf16, single dispatch, full K) --------
// grid (256, KS2); block 256 = 4 waves (2 m-tiles x 2 n-halves of 80).
// All loads lane-contiguous 1KB streams; direct store to own partial.
__global__ __launch_bounds__(256) void k_gemm2c(
        const unsigned short* __restrict__ x1fh,
        const unsigned short* __restrict__ w2fh, const unsigned short* __restrict__ w2fl,
        float* __restrict__ P){
    int wave = threadIdx.x >> 6, lane = threadIdx.x & 63;
    int wm = wave & 1, wn = wave >> 1;
    int q = lane >> 4, l16 = lane & 15;
    int mtile = blockIdx.x*2 + wm;
    int ks2 = blockIdx.y;
    int ks0 = ks2 * 64;
    const unsigned short* Ah = x1fh + ((size_t)mtile*128 + ks0)*512 + lane*8;
    const unsigned short* Bh = w2fh + ((size_t)ks0*10 + wn*5)*512 + lane*8;
    const unsigned short* Bl = w2fl + ((size_t)ks0*10 + wn*5)*512 + lane*8;
    f32x4 acc[5] = {};
    #pragma unroll 8
    for (int t = 0; t < 64; t++){
        bf16x8 ah = *(const bf16x8*)(Ah + (size_t)t*512);
        bf16x8 bh[5], bl[5];
        #pragma unroll
        for (int ni=0;ni<5;ni++){
            bh[ni] = *(const bf16x8*)(Bh + (size_t)(t*10 + ni)*512);
            bl[ni] = *(const bf16x8*)(Bl + (size_t)(t*10 + ni)*512);
        }
        #pragma unroll
        for (int ni=0;ni<5;ni++){
            acc[ni] = __builtin_amdgcn_mfma_f32_16x16x32_bf16(ah, bh[ni], acc[ni], 0,0,0);
            acc[ni] = __builtin_amdgcn_mfma_f32_16x16x32_bf16(ah, bl[ni], acc[ni], 0,0,0);
        }
    }
    float* outp = P + (size_t)ks2 * N_NODES * F2;
    #pragma unroll
    for (int ni=0;ni<5;ni++)
        #pragma unroll
        for (int i=0;i<4;i++)
            outp[(size_t)(mtile*16 + q*4 + i)*F2 + wn*80 + ni*16 + l16] = acc[ni][i];
}

// ---------------- reduce KS2 partials -> h2 ----------------
__global__ __launch_bounds__(256) void k_reduce(const float* __restrict__ P,
                                                float* __restrict__ h2){
    const int NV = N_NODES*F2/4;
    int i = blockIdx.x*256 + threadIdx.x;
    float4 a = ((const float4*)P)[i];
    #pragma unroll
    for (int kb = 1; kb < KS2; kb++){
        float4 b = ((const float4*)P)[(size_t)kb*NV + i];
        a.x += b.x; a.y += b.y; a.z += b.z; a.w += b.w;
    }
    ((float4*)h2)[i] = a;
}

// ---------------- attention dots, layer 2 ----------------
__global__ __launch_bounds__(64) void k_alpha2(const float* __restrict__ h2,
        const float* __restrict__ att_s, const float* __restrict__ att_d,
        float* __restrict__ as2, float* __restrict__ ad2){
    int n = blockIdx.x, t = threadIdx.x;
    float ps = 0.f, pd = 0.f;
    if (t < 40){
        float4 h = *(const float4*)(h2 + (size_t)n*F2 + t*4);
        float4 a = ((const float4*)att_s)[t];
        float4 d = ((const float4*)att_d)[t];
        ps = h.x*a.x + h.y*a.y + h.z*a.z + h.w*a.w;
        pd = h.x*d.x + h.y*d.y + h.z*d.z + h.w*d.w;
    }
    ps += __shfl_xor(ps,1); ps += __shfl_xor(ps,2); ps += __shfl_xor(ps,4);
    pd += __shfl_xor(pd,1); pd += __shfl_xor(pd,2); pd += __shfl_xor(pd,4);
    if (t < 40 && (t & 7) == 0){
        as2[n*NH2 + (t>>3)] = ps;
        ad2[n*NH2 + (t>>3)] = pd;
    }
}

// ------- layer-2 softmax + aggregation + head-mean + b2 ----------------------
__global__ __launch_bounds__(256) void k_agg2(const float* __restrict__ h2,
        const float* __restrict__ as2, const float* __restrict__ ad2,
        const int* __restrict__ row_start, const int* __restrict__ csr_src,
        const float* __restrict__ b2, float* __restrict__ x2){
    int n = blockIdx.x, t = threadIdx.x;
    __shared__ float ad_s[NH2], den_s[NH2], sacc[F2];
    int e0 = row_start[n], e1 = row_start[n+1];
    if (t < NH2) ad_s[t] = ad2[n*NH2 + t];
    __syncthreads();
    if (t < NH2){
        float d = 0.f;
        for (int e=e0;e<e1;e++){
            int s = csr_src[e];
            d += expf(lrelu(as2[s*NH2 + t] + ad_s[t]));
        }
        den_s[t] = d;
    }
    __syncthreads();
    if (t < F2){
        int h = t >> 5;
        float adh  = ad_s[h];
        float dinv = 1.f/den_s[h];
        float acc = 0.f;
        for (int e=e0;e<e1;e++){
            int s = csr_src[e];
            float w = expf(lrelu(as2[s*NH2 + h] + adh)) * dinv;
            acc += w * h2[(size_t)s*F2 + t];
        }
        sacc[t] = acc;
    }
    __syncthreads();
    if (t < OUT_F){
        float v = (sacc[t] + sacc[t+32] + sacc[t+64] + sacc[t+96] + sacc[t+128]) * 0.2f + b2[t];
        x2[n*OUT_F + t] = v;
    }
}

// ---------------- bond scores + softmax over 64 bonds ----------------
__global__ __launch_bounds__(64) void k_bond(const float* __restrict__ x2,
        const int* __restrict__ lefts, const int* __restrict__ rights,
        float* __restrict__ out){
    int b = threadIdx.x;
    int L = lefts[b], R = rights[b];
    float s = 0.f;
    #pragma unroll
    for (int c=0;c<OUT_F;c+=4){
        float4 l4 = *(const float4*)(x2 + (size_t)L*OUT_F + c);
        float4 r4 = *(const float4*)(x2 + (size_t)R*OUT_F + c);
        s += l4.x+l4.y+l4.z+l4.w + r4.x+r4.y+r4.z+r4.w;
    }
    float m = s;
    #pragma unroll
    for (int off=1; off<64; off<<=1) m = fmaxf(m, __shfl_xor(m, off));
    float e = expf(s - m);
    float sum = e;
    #pragma unroll
    for (int off=1; off<64; off<<=1) sum += __shfl_xor(sum, off);
    out[b] = e / sum;
}

extern "C" void kernel_launch(void* const* d_in, const int* in_sizes, int n_in,
                              void* d_out, int out_size, void* d_ws, size_t ws_size,
                              hipStream_t stream){
    const float* x      = (const float*)d_in[0];
    const int*   ei     = (const int*)  d_in[1];
    const int*   lefts  = (const int*)  d_in[2];
    const int*   rights = (const int*)  d_in[3];
    const float* W1     = (const float*)d_in[4];
    const float* att_s1 = (const float*)d_in[5];
    const float* att_d1 = (const float*)d_in[6];
    const float* b1     = (const float*)d_in[7];
    const float* W2     = (const float*)d_in[8];
    const float* att_s2 = (const float*)d_in[9];
    const float* att_d2 = (const float*)d_in[10];
    const float* b2     = (const float*)d_in[11];
    float* out = (float*)d_out;

    // fixed layout ~224 MB (ws_size ~268 MB, measured from harness fill)
    char* ws = (char*)d_ws;
    size_t off = 0;
    auto alloc = [&](size_t bytes) -> void* {
        void* p = ws + off;
        off += (bytes + 255) & ~(size_t)255;
        return p;
    };
    unsigned short* txhi = (unsigned short*)alloc((size_t)NH1*N_NODES*IN_F*2); // 134 MB
    unsigned short* x1fh = (unsigned short*)alloc((size_t)N_NODES*F1*2);       // 67 MB frag
    float* part   = (float*)alloc((size_t)KS2*N_NODES*F2*4);                   // 10.5 MB
    float* h2     = (float*)alloc((size_t)N_NODES*F2*4);
    float* as1    = (float*)alloc((size_t)N_NODES*NH1*4);
    float* ad1    = (float*)alloc((size_t)N_NODES*NH1*4);
    float* as2    = (float*)alloc((size_t)N_NODES*NH2*4);
    float* ad2    = (float*)alloc((size_t)N_NODES*NH2*4);
    float* x2     = (float*)alloc((size_t)N_NODES*OUT_F*4);
    float* vsT    = (float*)alloc((size_t)IN_F*NH1*4);
    float* vdT    = (float*)alloc((size_t)IN_F*NH1*4);
    unsigned short* w1fh = (unsigned short*)alloc((size_t)F1*IN_F*2);
    unsigned short* w1fl = (unsigned short*)alloc((size_t)F1*IN_F*2);
    unsigned short* w2fh = (unsigned short*)alloc((size_t)128*10*512*2);
    unsigned short* w2fl = (unsigned short*)alloc((size_t)128*10*512*2);
    int* counts    = (int*)alloc((size_t)N_NODES*4);
    int* row_start = (int*)alloc((size_t)(N_NODES+1)*4);
    int* cursor    = (int*)alloc((size_t)N_NODES*4);
    int* csr_src   = (int*)alloc((size_t)E_TOT*4);

    // CSR by destination
    k_init_counts<<<32, 256, 0, stream>>>(counts);
    k_count<<<192, 256, 0, stream>>>(ei, counts);
    k_scan<<<1, 1024, 0, stream>>>(counts, row_start, cursor);
    k_fill<<<224, 256, 0, stream>>>(ei, cursor, csr_src);

    // fragment-order split-bf16 weight packs (direct from fp32)
    k_packw1d<<<65536/256, 256, 0, stream>>>(W1, w1fh, w1fl);
    k_packw2d<<<81920/256, 256, 0, stream>>>(W2, w2fh, w2fl);

    // alpha dots (once, from x); denominators fused into k_aggx64
    k_attvec<<<NH1, 128, 0, stream>>>(W1, att_s1, att_d1, vsT, vdT);
    k_alpha1x<<<N_NODES, 128, 0, stream>>>(x, vsT, vdT, as1, ad1);

    // layer 1: single-pass aggregation (all heads) + per-head MFMA projection
    k_aggx64<<<N_NODES, 256, 0, stream>>>(x, as1, ad1, row_start, csr_src, txhi);
    k_gemm1h<<<dim3(64, NH1), 256, 0, stream>>>(txhi, w1fh, w1fl, b1, x1fh);

    // layer-2 projection (single dispatch, full K) + reduce
    k_gemm2c<<<dim3(256, KS2), 256, 0, stream>>>(x1fh, w2fh, w2fl, part);
    k_reduce<<<N_NODES*F2/4/256, 256, 0, stream>>>(part, h2);

    k_alpha2<<<N_NODES, 64, 0, stream>>>(h2, att_s2, att_d2, as2, ad2);
    k_agg2<<<N_NODES, 256, 0, stream>>>(h2, as2, ad2, row_start, csr_src, b2, x2);

    k_bond<<<1, 64, 0, stream>>>(x2, lefts, rights, out);
}

// Round 19
// 308.474 us; speedup vs baseline: 1.6778x; 1.0890x over previous
//
#include <hip/hip_runtime.h>
#include <hip/hip_bf16.h>
#include <math.h>

#define N_NODES  8192
#define N_EDGES  49152
#define E_TOT    57344   // edges + self-loops
#define IN_F     128
#define HID      64
#define NH1      64
#define NH2      5
#define OUT_F    32
#define F1       4096    // NH1*HID
#define F2       160     // NH2*OUT_F
#define N_BONDS  64
#define ET       16      // aggx edge-tile
#define KS2      8       // gemm2 k-split (8 -> 2048 blocks = full occupancy)

typedef short bf16x8 __attribute__((ext_vector_type(8)));
typedef float f32x4  __attribute__((ext_vector_type(4)));

__device__ __forceinline__ float lrelu(float x){ return x > 0.f ? x : 0.2f*x; }

__device__ __forceinline__ unsigned short bf16_rne(float f){
    unsigned u = __float_as_uint(f);
    unsigned r = u + 0x7FFF + ((u >> 16) & 1);
    return (unsigned short)(r >> 16);
}
__device__ __forceinline__ float bf16f(unsigned short h){
    return __uint_as_float((unsigned)h << 16);
}

// ---------------- CSR build (sort edges by dst) ----------------
__global__ void k_init_counts(int* counts){
    int i = blockIdx.x*256 + threadIdx.x;
    if (i < N_NODES) counts[i] = 1;   // self-loop
}
__global__ void k_count(const int* __restrict__ ei, int* counts){
    int i = blockIdx.x*256 + threadIdx.x;
    if (i < N_EDGES) atomicAdd(&counts[ei[N_EDGES + i]], 1);
}
__global__ __launch_bounds__(1024) void k_scan(const int* __restrict__ counts,
                                               int* __restrict__ row_start,
                                               int* __restrict__ cursor){
    __shared__ int sd[1024];
    int t = threadIdx.x;
    int v[8]; int sum = 0;
    #pragma unroll
    for (int i=0;i<8;i++){ v[i] = counts[t*8+i]; sum += v[i]; }
    sd[t] = sum; __syncthreads();
    for (int off=1; off<1024; off<<=1){
        int vv = (t >= off) ? sd[t-off] : 0;
        __syncthreads();
        sd[t] += vv;
        __syncthreads();
    }
    int run = sd[t] - sum;  // exclusive prefix
    #pragma unroll
    for (int i=0;i<8;i++){ row_start[t*8+i] = run; cursor[t*8+i] = run; run += v[i]; }
    if (t == 1023) row_start[N_NODES] = run;
}
__global__ void k_fill(const int* __restrict__ ei, int* cursor, int* __restrict__ csr_src){
    int i = blockIdx.x*256 + threadIdx.x;
    if (i >= E_TOT) return;
    int s, d;
    if (i < N_EDGES){ s = ei[i]; d = ei[N_EDGES + i]; }
    else { s = i - N_EDGES; d = s; }
    int pos = atomicAdd(&cursor[d], 1);
    csr_src[pos] = s;
}

// ---- pack W1 fp32 -> split-bf16 B-fragment order: [hg][ks][ct][lane][8] ----
__global__ void k_packw1d(const float* __restrict__ W1,
                          unsigned short* __restrict__ fh, unsigned short* __restrict__ fl){
    int g = blockIdx.x*256 + threadIdx.x;            // 64*4*4*64 = 65536 groups
    int lane = g & 63, ct = (g >> 6) & 3, ks = (g >> 8) & 3, hg = g >> 10;
    int col = hg*64 + ct*16 + (lane & 15);
    int k = ks*32 + (lane >> 4)*8;
    const float* src = W1 + (size_t)col*IN_F + k;
    bf16x8 hv, lv;
    #pragma unroll
    for (int j=0;j<8;j++){
        float f = src[j];
        unsigned short hb = bf16_rne(f);
        hv[j] = (short)hb;
        lv[j] = (short)bf16_rne(f - bf16f(hb));
    }
    *(bf16x8*)(fh + (size_t)g*8) = hv;
    *(bf16x8*)(fl + (size_t)g*8) = lv;
}

// ---- pack W2 fp32 -> split-bf16 B-fragment order: [kc][ni][lane][8] ----
__global__ void k_packw2d(const float* __restrict__ W2,
                          unsigned short* __restrict__ fh, unsigned short* __restrict__ fl){
    int g = blockIdx.x*256 + threadIdx.x;            // 128*10*64 = 81920 groups
    int lane = g & 63, ni = (g >> 6) % 10, kc = g / 640;
    int n = ni*16 + (lane & 15);
    int k = kc*32 + (lane >> 4)*8;
    const float* src = W2 + (size_t)n*F1 + k;
    bf16x8 hv, lv;
    #pragma unroll
    for (int j=0;j<8;j++){
        float f = src[j];
        unsigned short hb = bf16_rne(f);
        hv[j] = (short)hb;
        lv[j] = (short)bf16_rne(f - bf16f(hb));
    }
    *(bf16x8*)(fh + (size_t)g*8) = hv;
    *(bf16x8*)(fl + (size_t)g*8) = lv;
}

// ------- attention vectors: vsT[k][h] = sum_c a_s[h,c] * W1[h*64+c, k] -------
__global__ __launch_bounds__(128) void k_attvec(const float* __restrict__ W1,
        const float* __restrict__ a_s, const float* __restrict__ a_d,
        float* __restrict__ vsT, float* __restrict__ vdT){
    int h = blockIdx.x, k = threadIdx.x;
    float s = 0.f, d = 0.f;
    for (int c = 0; c < HID; c++){
        float w = W1[(size_t)(h*HID + c)*IN_F + k];
        s += a_s[h*HID + c] * w;
        d += a_d[h*HID + c] * w;
    }
    vsT[k*NH1 + h] = s;
    vdT[k*NH1 + h] = d;
}

// ---------- alpha dots from x: as1[n,h] = x[n,:] . vsT[:,h] ------------------
__global__ __launch_bounds__(128) void k_alpha1x(const float* __restrict__ x,
        const float* __restrict__ vsT, const float* __restrict__ vdT,
        float* __restrict__ as1, float* __restrict__ ad1){
    int n = blockIdx.x, t = threadIdx.x;
    __shared__ float xs[IN_F];
    xs[t] = x[(size_t)n*IN_F + t];
    __syncthreads();
    if (t < NH1){
        float s = 0.f, d = 0.f;
        for (int k = 0; k < IN_F; k++){
            float xv = xs[k];
            s += xv * vsT[k*NH1 + t];
            d += xv * vdT[k*NH1 + t];
        }
        as1[n*NH1 + t] = s;
        ad1[n*NH1 + t] = d;
    }
}

// ------- x-space aggregation, ALL 64 heads, denom fused, single dispatch -----
// Block per dst node, 256 thr: head-quad hq = t>>4 (4 heads), f0 = (t&15)*8.
// Output: bf16 hi-plane, contiguous 256B runs per (head, node).
__global__ __launch_bounds__(256) void k_aggx64(const float* __restrict__ x,
        const float* __restrict__ as1, const float* __restrict__ ad1,
        const int* __restrict__ row_start, const int* __restrict__ csr_src,
        unsigned short* __restrict__ txhi){
    int n = blockIdx.x, t = threadIdx.x;
    __shared__ float ad_s[NH1];
    __shared__ float wt[ET][NH1];   // 4 KB
    __shared__ int   st[ET];
    __shared__ float xs[ET][IN_F];  // 8 KB
    int e0 = row_start[n], e1 = row_start[n+1];
    if (t < NH1) ad_s[t] = ad1[n*NH1 + t];
    int hq = t >> 4, f0 = (t & 15)*8;
    float acc[4][8] = {};
    float D[4] = {0.f, 0.f, 0.f, 0.f};
    for (int eb = e0; eb < e1; eb += ET){
        int ne = min(ET, e1 - eb);
        if (t < ne) st[t] = csr_src[eb + t];
        __syncthreads();
        for (int idx = t; idx < ne*32; idx += 256){
            int e = idx >> 5, f4 = idx & 31;
            *(float4*)&xs[e][f4*4] = *(const float4*)(x + (size_t)st[e]*IN_F + f4*4);
        }
        for (int idx = t; idx < ne*NH1; idx += 256){
            int e = idx >> 6, hh = idx & 63;
            wt[e][hh] = expf(lrelu(as1[st[e]*NH1 + hh] + ad_s[hh]));
        }
        __syncthreads();
        for (int e = 0; e < ne; e++){
            float4 v0 = *(const float4*)&xs[e][f0];
            float4 v1 = *(const float4*)&xs[e][f0+4];
            float xv[8] = {v0.x,v0.y,v0.z,v0.w,v1.x,v1.y,v1.z,v1.w};
            #pragma unroll
            for (int c=0;c<4;c++){
                float w = wt[e][hq*4 + c];
                D[c] += w;
                #pragma unroll
                for (int j=0;j<8;j++) acc[c][j] += w*xv[j];
            }
        }
        __syncthreads();
    }
    #pragma unroll
    for (int c=0;c<4;c++){
        float dinv = 1.f / D[c];
        bf16x8 hv;
        #pragma unroll
        for (int j=0;j<8;j++) hv[j] = (short)bf16_rne(acc[c][j] * dinv);
        size_t o = ((size_t)(hq*4 + c)*N_NODES + n)*IN_F + f0;
        *(bf16x8*)(txhi + o) = hv;
    }
}

// ------- per-head GEMM (MFMA: A bf16 x B split-bf16) + bias/ELU --------------
// grid (64, 64); 4 waves 2x2; wave tile 64 rows x 32 cols, K=128.
__global__ __launch_bounds__(256) void k_gemm1h(const unsigned short* __restrict__ txhi,
        const unsigned short* __restrict__ w1fh,
        const unsigned short* __restrict__ w1fl,
        const float* __restrict__ b1,
        unsigned short* __restrict__ x1fh){
    __shared__ unsigned short hs[4][64][36];
    int wave = threadIdx.x >> 6, lane = threadIdx.x & 63;
    int wm = wave & 1, wn = wave >> 1;
    int hg = blockIdx.y;
    int m0 = blockIdx.x * 128;
    int q = lane >> 4, l16 = lane & 15;
    const unsigned short* Ah = txhi + (size_t)hg*N_NODES*IN_F;
    f32x4 acc[4][2] = {};
    #pragma unroll
    for (int ks = 0; ks < 4; ks++){
        int kb = ks*32 + q*8;
        bf16x8 ah[4], bh[2], bl[2];
        #pragma unroll
        for (int mi=0;mi<4;mi++){
            size_t r = (size_t)(m0 + wm*64 + mi*16 + l16)*IN_F + kb;
            ah[mi] = *(const bf16x8*)(Ah + r);
        }
        #pragma unroll
        for (int ni=0;ni<2;ni++){
            size_t r = (((size_t)hg*4 + ks)*4 + wn*2 + ni)*512 + lane*8;
            bh[ni] = *(const bf16x8*)(w1fh + r);
            bl[ni] = *(const bf16x8*)(w1fl + r);
        }
        #pragma unroll
        for (int mi=0;mi<4;mi++)
            #pragma unroll
            for (int ni=0;ni<2;ni++){
                acc[mi][ni] = __builtin_amdgcn_mfma_f32_16x16x32_bf16(ah[mi], bh[ni], acc[mi][ni], 0,0,0);
                acc[mi][ni] = __builtin_amdgcn_mfma_f32_16x16x32_bf16(ah[mi], bl[ni], acc[mi][ni], 0,0,0);
            }
    }
    // bias + ELU -> per-wave LDS tile [64 rows][32 cols]
    #pragma unroll
    for (int mi=0;mi<4;mi++)
        #pragma unroll
        for (int ni=0;ni<2;ni++){
            int c = wn*32 + ni*16 + l16;
            float b = b1[hg*64 + c];
            #pragma unroll
            for (int i=0;i<4;i++){
                float v = acc[mi][ni][i] + b;
                float o = v > 0.f ? v : expm1f(v);
                int rr = mi*16 + q*4 + i;
                hs[wave][rr][ni*16 + l16] = bf16_rne(o);
            }
        }
    __syncthreads();
    // LDS -> fragment-order write (gemm2 A-frag); 1KB-contiguous runs.
    int ksg = hg*2 + wn;
    #pragma unroll
    for (int mi=0;mi<4;mi++){
        int mtile = blockIdx.x*8 + wm*4 + mi;
        bf16x8 fh = *(const bf16x8*)&hs[wave][mi*16 + l16][q*8];
        size_t o = ((size_t)mtile*128 + ksg)*512 + lane*8;
        *(bf16x8*)(x1fh + o) = fh;
    }
}

// ------- GEMM2 (MFMA: A bf16 x B split-bf16, full occupancy via KS2=8) -------
// grid (256, KS2=8) = 2048 blocks = 8 blocks/CU = 32 waves/CU.
// Block = 4 waves (2 m-tiles x 2 n-halves of 80); 16 k-steps, fully unrolled.
// All loads lane-contiguous 1KB streams; direct store to own partial.
__global__ __launch_bounds__(256) void k_gemm2c(
        const unsigned short* __restrict__ x1fh,
        const unsigned short* __restrict__ w2fh, const unsigned short* __restrict__ w2fl,
        float* __restrict__ P){
    int wave = threadIdx.x >> 6, lane = threadIdx.x & 63;
    int wm = wave & 1, wn = wave >> 1;
    int q = lane >> 4, l16 = lane & 15;
    int mtile = blockIdx.x*2 + wm;
    int ks2 = blockIdx.y;
    int ks0 = ks2 * (128/KS2);
    const unsigned short* Ah = x1fh + ((size_t)mtile*128 + ks0)*512 + lane*8;
    const unsigned short* Bh = w2fh + ((size_t)ks0*10 + wn*5)*512 + lane*8;
    const unsigned short* Bl = w2fl + ((size_t)ks0*10 + wn*5)*512 + lane*8;
    f32x4 acc[5] = {};
    #pragma unroll
    for (int t = 0; t < 128/KS2; t++){
        bf16x8 ah = *(const bf16x8*)(Ah + (size_t)t*512);
        bf16x8 bh[5], bl[5];
        #pragma unroll
        for (int ni=0;ni<5;ni++){
            bh[ni] = *(const bf16x8*)(Bh + (size_t)(t*10 + ni)*512);
            bl[ni] = *(const bf16x8*)(Bl + (size_t)(t*10 + ni)*512);
        }
        #pragma unroll
        for (int ni=0;ni<5;ni++){
            acc[ni] = __builtin_amdgcn_mfma_f32_16x16x32_bf16(ah, bh[ni], acc[ni], 0,0,0);
            acc[ni] = __builtin_amdgcn_mfma_f32_16x16x32_bf16(ah, bl[ni], acc[ni], 0,0,0);
        }
    }
    float* outp = P + (size_t)ks2 * N_NODES * F2;
    #pragma unroll
    for (int ni=0;ni<5;ni++)
        #pragma unroll
        for (int i=0;i<4;i++)
            outp[(size_t)(mtile*16 + q*4 + i)*F2 + wn*80 + ni*16 + l16] = acc[ni][i];
}

// ---------------- reduce KS2 partials -> h2 ----------------
__global__ __launch_bounds__(256) void k_reduce(const float* __restrict__ P,
                                                float* __restrict__ h2){
    const int NV = N_NODES*F2/4;
    int i = blockIdx.x*256 + threadIdx.x;
    float4 a = ((const float4*)P)[i];
    #pragma unroll
    for (int kb = 1; kb < KS2; kb++){
        float4 b = ((const float4*)P)[(size_t)kb*NV + i];
        a.x += b.x; a.y += b.y; a.z += b.z; a.w += b.w;
    }
    ((float4*)h2)[i] = a;
}

// ---------------- attention dots, layer 2 ----------------
__global__ __launch_bounds__(64) void k_alpha2(const float* __restrict__ h2,
        const float* __restrict__ att_s, const float* __restrict__ att_d,
        float* __restrict__ as2, float* __restrict__ ad2){
    int n = blockIdx.x, t = threadIdx.x;
    float ps = 0.f, pd = 0.f;
    if (t < 40){
        float4 h = *(const float4*)(h2 + (size_t)n*F2 + t*4);
        float4 a = ((const float4*)att_s)[t];
        float4 d = ((const float4*)att_d)[t];
        ps = h.x*a.x + h.y*a.y + h.z*a.z + h.w*a.w;
        pd = h.x*d.x + h.y*d.y + h.z*d.z + h.w*d.w;
    }
    ps += __shfl_xor(ps,1); ps += __shfl_xor(ps,2); ps += __shfl_xor(ps,4);
    pd += __shfl_xor(pd,1); pd += __shfl_xor(pd,2); pd += __shfl_xor(pd,4);
    if (t < 40 && (t & 7) == 0){
        as2[n*NH2 + (t>>3)] = ps;
        ad2[n*NH2 + (t>>3)] = pd;
    }
}

// ------- layer-2 softmax + aggregation + head-mean + b2 ----------------------
__global__ __launch_bounds__(256) void k_agg2(const float* __restrict__ h2,
        const float* __restrict__ as2, const float* __restrict__ ad2,
        const int* __restrict__ row_start, const int* __restrict__ csr_src,
        const float* __restrict__ b2, float* __restrict__ x2){
    int n = blockIdx.x, t = threadIdx.x;
    __shared__ float ad_s[NH2], den_s[NH2], sacc[F2];
    int e0 = row_start[n], e1 = row_start[n+1];
    if (t < NH2) ad_s[t] = ad2[n*NH2 + t];
    __syncthreads();
    if (t < NH2){
        float d = 0.f;
        for (int e=e0;e<e1;e++){
            int s = csr_src[e];
            d += expf(lrelu(as2[s*NH2 + t] + ad_s[t]));
        }
        den_s[t] = d;
    }
    __syncthreads();
    if (t < F2){
        int h = t >> 5;
        float adh  = ad_s[h];
        float dinv = 1.f/den_s[h];
        float acc = 0.f;
        for (int e=e0;e<e1;e++){
            int s = csr_src[e];
            float w = expf(lrelu(as2[s*NH2 + h] + adh)) * dinv;
            acc += w * h2[(size_t)s*F2 + t];
        }
        sacc[t] = acc;
    }
    __syncthreads();
    if (t < OUT_F){
        float v = (sacc[t] + sacc[t+32] + sacc[t+64] + sacc[t+96] + sacc[t+128]) * 0.2f + b2[t];
        x2[n*OUT_F + t] = v;
    }
}

// ---------------- bond scores + softmax over 64 bonds ----------------
__global__ __launch_bounds__(64) void k_bond(const float* __restrict__ x2,
        const int* __restrict__ lefts, const int* __restrict__ rights,
        float* __restrict__ out){
    int b = threadIdx.x;
    int L = lefts[b], R = rights[b];
    float s = 0.f;
    #pragma unroll
    for (int c=0;c<OUT_F;c+=4){
        float4 l4 = *(const float4*)(x2 + (size_t)L*OUT_F + c);
        float4 r4 = *(const float4*)(x2 + (size_t)R*OUT_F + c);
        s += l4.x+l4.y+l4.z+l4.w + r4.x+r4.y+r4.z+r4.w;
    }
    float m = s;
    #pragma unroll
    for (int off=1; off<64; off<<=1) m = fmaxf(m, __shfl_xor(m, off));
    float e = expf(s - m);
    float sum = e;
    #pragma unroll
    for (int off=1; off<64; off<<=1) sum += __shfl_xor(sum, off);
    out[b] = e / sum;
}

extern "C" void kernel_launch(void* const* d_in, const int* in_sizes, int n_in,
                              void* d_out, int out_size, void* d_ws, size_t ws_size,
                              hipStream_t stream){
    const float* x      = (const float*)d_in[0];
    const int*   ei     = (const int*)  d_in[1];
    const int*   lefts  = (const int*)  d_in[2];
    const int*   rights = (const int*)  d_in[3];
    const float* W1     = (const float*)d_in[4];
    const float* att_s1 = (const float*)d_in[5];
    const float* att_d1 = (const float*)d_in[6];
    const float* b1     = (const float*)d_in[7];
    const float* W2     = (const float*)d_in[8];
    const float* att_s2 = (const float*)d_in[9];
    const float* att_d2 = (const float*)d_in[10];
    const float* b2     = (const float*)d_in[11];
    float* out = (float*)d_out;

    // fixed layout ~259 MB (ws_size >= 268.4 MB, measured from harness fill)
    char* ws = (char*)d_ws;
    size_t off = 0;
    auto alloc = [&](size_t bytes) -> void* {
        void* p = ws + off;
        off += (bytes + 255) & ~(size_t)255;
        return p;
    };
    unsigned short* txhi = (unsigned short*)alloc((size_t)NH1*N_NODES*IN_F*2); // 134 MB
    unsigned short* x1fh = (unsigned short*)alloc((size_t)N_NODES*F1*2);       // 67 MB frag
    float* part   = (float*)alloc((size_t)KS2*N_NODES*F2*4);                   // 42 MB
    float* h2     = (float*)alloc((size_t)N_NODES*F2*4);
    float* as1    = (float*)alloc((size_t)N_NODES*NH1*4);
    float* ad1    = (float*)alloc((size_t)N_NODES*NH1*4);
    float* as2    = (float*)alloc((size_t)N_NODES*NH2*4);
    float* ad2    = (float*)alloc((size_t)N_NODES*NH2*4);
    float* x2     = (float*)alloc((size_t)N_NODES*OUT_F*4);
    float* vsT    = (float*)alloc((size_t)IN_F*NH1*4);
    float* vdT    = (float*)alloc((size_t)IN_F*NH1*4);
    unsigned short* w1fh = (unsigned short*)alloc((size_t)F1*IN_F*2);
    unsigned short* w1fl = (unsigned short*)alloc((size_t)F1*IN_F*2);
    unsigned short* w2fh = (unsigned short*)alloc((size_t)128*10*512*2);
    unsigned short* w2fl = (unsigned short*)alloc((size_t)128*10*512*2);
    int* counts    = (int*)alloc((size_t)N_NODES*4);
    int* row_start = (int*)alloc((size_t)(N_NODES+1)*4);
    int* cursor    = (int*)alloc((size_t)N_NODES*4);
    int* csr_src   = (int*)alloc((size_t)E_TOT*4);

    // CSR by destination
    k_init_counts<<<32, 256, 0, stream>>>(counts);
    k_count<<<192, 256, 0, stream>>>(ei, counts);
    k_scan<<<1, 1024, 0, stream>>>(counts, row_start, cursor);
    k_fill<<<224, 256, 0, stream>>>(ei, cursor, csr_src);

    // fragment-order split-bf16 weight packs (direct from fp32)
    k_packw1d<<<65536/256, 256, 0, stream>>>(W1, w1fh, w1fl);
    k_packw2d<<<81920/256, 256, 0, stream>>>(W2, w2fh, w2fl);

    // alpha dots (once, from x); denominators fused into k_aggx64
    k_attvec<<<NH1, 128, 0, stream>>>(W1, att_s1, att_d1, vsT, vdT);
    k_alpha1x<<<N_NODES, 128, 0, stream>>>(x, vsT, vdT, as1, ad1);

    // layer 1: single-pass aggregation (all heads) + per-head MFMA projection
    k_aggx64<<<N_NODES, 256, 0, stream>>>(x, as1, ad1, row_start, csr_src, txhi);
    k_gemm1h<<<dim3(64, NH1), 256, 0, stream>>>(txhi, w1fh, w1fl, b1, x1fh);

    // layer-2 projection (full occupancy) + reduce
    k_gemm2c<<<dim3(256, KS2), 256, 0, stream>>>(x1fh, w2fh, w2fl, part);
    k_reduce<<<N_NODES*F2/4/256, 256, 0, stream>>>(part, h2);

    k_alpha2<<<N_NODES, 64, 0, stream>>>(h2, att_s2, att_d2, as2, ad2);
    k_agg2<<<N_NODES, 256, 0, stream>>>(h2, as2, ad2, row_start, csr_src, b2, x2);

    k_bond<<<1, 64, 0, stream>>>(x2, lefts, rights, out);
}